// Round 13
// baseline (980.784 us; speedup 1.0000x reference)
//
#include <hip/hip_runtime.h>
#include <math.h>

// Problem constants
#define BB 64
#define NN 100
#define HH 128
#define T3 384

// Output layout (floats, concatenated in return order)
#define O0 0            // sample_logprob [64,99]
#define O1 6336         // sample_distance [64,1]
#define O2 6400         // greedy_distance [64,1]
#define O3 6464         // predict_matrix [64,100,100,2]
#define O4 1286464      // greedy_solution_matrix [64,100,100]

#define TINYF 1.17549435e-38f
#define SCALEF 0.08838834764831845f

// ---------------- threefry2x32 (exact JAX implementation) ----------------
__device__ __forceinline__ unsigned rotl32(unsigned x, int d) {
    return (x << d) | (x >> (32 - d));
}

__device__ __forceinline__ void tf2x32(unsigned ks0, unsigned ks1,
                                       unsigned x0, unsigned x1,
                                       unsigned& o0, unsigned& o1) {
    unsigned ks2 = ks0 ^ ks1 ^ 0x1BD11BDAu;
    x0 += ks0; x1 += ks1;
    x0 += x1; x1 = rotl32(x1, 13); x1 ^= x0;
    x0 += x1; x1 = rotl32(x1, 15); x1 ^= x0;
    x0 += x1; x1 = rotl32(x1, 26); x1 ^= x0;
    x0 += x1; x1 = rotl32(x1, 6);  x1 ^= x0;
    x0 += ks1; x1 += ks2 + 1u;
    x0 += x1; x1 = rotl32(x1, 17); x1 ^= x0;
    x0 += x1; x1 = rotl32(x1, 29); x1 ^= x0;
    x0 += x1; x1 = rotl32(x1, 16); x1 ^= x0;
    x0 += x1; x1 = rotl32(x1, 24); x1 ^= x0;
    x0 += ks2; x1 += ks0 + 2u;
    x0 += x1; x1 = rotl32(x1, 13); x1 ^= x0;
    x0 += x1; x1 = rotl32(x1, 15); x1 ^= x0;
    x0 += x1; x1 = rotl32(x1, 26); x1 ^= x0;
    x0 += x1; x1 = rotl32(x1, 6);  x1 ^= x0;
    x0 += ks0; x1 += ks1 + 3u;
    x0 += x1; x1 = rotl32(x1, 17); x1 ^= x0;
    x0 += x1; x1 = rotl32(x1, 29); x1 ^= x0;
    x0 += x1; x1 = rotl32(x1, 16); x1 ^= x0;
    x0 += x1; x1 = rotl32(x1, 24); x1 ^= x0;
    x0 += ks1; x1 += ks2 + 4u;
    x0 += x1; x1 = rotl32(x1, 13); x1 ^= x0;
    x0 += x1; x1 = rotl32(x1, 15); x1 ^= x0;
    x0 += x1; x1 = rotl32(x1, 26); x1 ^= x0;
    x0 += x1; x1 = rotl32(x1, 6);  x1 ^= x0;
    x0 += ks2; x1 += ks0 + 5u;
    o0 = x0; o1 = x1;
}

__device__ __forceinline__ float gumbel_f(unsigned k0, unsigned k1, unsigned f) {
    unsigned o0, o1;
    tf2x32(k0, k1, 0u, f, o0, o1);
    unsigned bits = o0 ^ o1;
    float u01 = __uint_as_float((bits >> 9) | 0x3F800000u) - 1.0f;
    float u = fmaxf(TINYF, u01 * (1.0f - TINYF) + TINYF);
    return -logf(-logf(u));
}

// ---------------- fused pre-kernel: embed + adj + transpose + predict + zero ----------
__global__ void k_pre0(const float* __restrict__ node, const float* __restrict__ demand,
                       const float* __restrict__ Wn0, const float* __restrict__ bn0,
                       const float* __restrict__ dis,
                       const float* __restrict__ We, const float* __restrict__ be,
                       const float* __restrict__ Wc, const float* __restrict__ bc,
                       const float* __restrict__ Wq,
                       float* __restrict__ h, float* __restrict__ A,
                       float* __restrict__ WqT,
                       float* __restrict__ out3, float* __restrict__ zp) {
    __shared__ float sWe[128], sbe[128], sc0[128], sc1[128];
    int bid = blockIdx.x, tid = threadIdx.x;
    if (bid < 3200) {
        int idx = bid * 256 + tid;
        int r = idx >> 7, c = idx & 127;
        float v = node[r * 2] * Wn0[c] + node[r * 2 + 1] * Wn0[128 + c]
                + demand[r] * Wn0[256 + c] + bn0[c];
        h[idx] = fmaxf(v, 0.0f);
    } else if (bid < 4800) {
        int row = (bid - 3200) * 4 + (tid >> 6);
        int l = tid & 63;
        const float* d = dis + row * NN;
        float v0 = -d[l];
        float v1 = (l + 64 < NN) ? -d[l + 64] : -__builtin_inff();
        float m = fmaxf(v0, v1);
        for (int off = 32; off > 0; off >>= 1) m = fmaxf(m, __shfl_xor(m, off));
        float e0 = expf(v0 - m);
        float e1 = (l + 64 < NN) ? expf(v1 - m) : 0.0f;
        float s = e0 + e1;
        for (int off = 32; off > 0; off >>= 1) s += __shfl_xor(s, off);
        float inv = 1.0f / s;
        A[row * NN + l] = e0 * inv;
        if (l + 64 < NN) A[row * NN + l + 64] = e1 * inv;
    } else if (bid < 4864) {
        int i = (bid - 4800) * 256 + tid;
        int k = i >> 7, c = i & 127;
        WqT[k * 128 + c] = Wq[c * 128 + k];
    } else if (bid < 6114) {
        if (tid < 128) {
            sWe[tid] = We[tid];
            sbe[tid] = be[tid];
            sc0[tid] = Wc[tid * 2];
            sc1[tid] = Wc[tid * 2 + 1];
        }
        __syncthreads();
        float b0 = bc[0], b1 = bc[1];
        int p0 = (bid - 4864) * 512 + tid, p1 = p0 + 256;
        float d0 = dis[p0], d1 = dis[p1];
        float a00 = b0, a01 = b1, a10 = b0, a11 = b1;
        for (int k4 = 0; k4 < 32; k4++) {
            float4 we = *(const float4*)&sWe[4 * k4];
            float4 bb = *(const float4*)&sbe[4 * k4];
            float4 c0 = *(const float4*)&sc0[4 * k4];
            float4 c1 = *(const float4*)&sc1[4 * k4];
            float e0, e1;
            e0 = fmaxf(d0 * we.x + bb.x, 0.0f); a00 += e0 * c0.x; a01 += e0 * c1.x;
            e1 = fmaxf(d1 * we.x + bb.x, 0.0f); a10 += e1 * c0.x; a11 += e1 * c1.x;
            e0 = fmaxf(d0 * we.y + bb.y, 0.0f); a00 += e0 * c0.y; a01 += e0 * c1.y;
            e1 = fmaxf(d1 * we.y + bb.y, 0.0f); a10 += e1 * c0.y; a11 += e1 * c1.y;
            e0 = fmaxf(d0 * we.z + bb.z, 0.0f); a00 += e0 * c0.z; a01 += e0 * c1.z;
            e1 = fmaxf(d1 * we.z + bb.z, 0.0f); a10 += e1 * c0.z; a11 += e1 * c1.z;
            e0 = fmaxf(d0 * we.w + bb.w, 0.0f); a00 += e0 * c0.w; a01 += e0 * c1.w;
            e1 = fmaxf(d1 * we.w + bb.w, 0.0f); a10 += e1 * c0.w; a11 += e1 * c1.w;
        }
        {
            float m = fmaxf(a00, a01);
            float q0 = expf(a00 - m), q1 = expf(a01 - m);
            float inv = 1.0f / (q0 + q1);
            out3[p0 * 2] = q0 * inv;
            out3[p0 * 2 + 1] = q1 * inv;
        }
        {
            float m = fmaxf(a10, a11);
            float q0 = expf(a10 - m), q1 = expf(a11 - m);
            float inv = 1.0f / (q0 + q1);
            out3[p1 * 2] = q0 * inv;
            out3[p1 * 2 + 1] = q1 * inv;
        }
    } else {
        int i = (bid - 6114) * 256 + tid;
        float4 z; z.x = 0.f; z.y = 0.f; z.z = 0.f; z.w = 0.f;
        ((float4*)zp)[i] = z;
    }
}

// out[6400x128] = h @ W[128x128]; 16 rows/block; float4 h reads, ordered FMAs
__global__ void k_hw16(const float* __restrict__ h, const float* __restrict__ W,
                       float* __restrict__ out) {
    __shared__ float hs[16 * 128];
    int block_row = blockIdx.x * 16;
    int tid = threadIdx.x;
    int col = tid & 127;
    int rg = tid >> 7;
    for (int i = tid; i < 16 * 32; i += 256)
        ((float4*)hs)[i] = ((const float4*)(h + block_row * 128))[i];
    __syncthreads();
    float acc[8] = {0.f, 0.f, 0.f, 0.f, 0.f, 0.f, 0.f, 0.f};
    for (int k4 = 0; k4 < 32; k4++) {
        int k = 4 * k4;
        float w0 = W[k * 128 + col], w1 = W[(k + 1) * 128 + col];
        float w2 = W[(k + 2) * 128 + col], w3 = W[(k + 3) * 128 + col];
#pragma unroll
        for (int r = 0; r < 8; r++) {
            float4 h4 = *(const float4*)&hs[(rg + 2 * r) * 128 + k];
            acc[r] += h4.x * w0; acc[r] += h4.y * w1;
            acc[r] += h4.z * w2; acc[r] += h4.w * w3;
        }
    }
#pragma unroll
    for (int r = 0; r < 8; r++)
        out[(block_row + rg + 2 * r) * 128 + col] = acc[r];
}

// fused Z (h@WqT) + P0 (h@Wih0+bih0); grid (400, 4); float4 h reads
__global__ void k_zp(const float* __restrict__ h, const float* __restrict__ WqT,
                     const float* __restrict__ Wih, const float* __restrict__ bih,
                     float* __restrict__ Z, float* __restrict__ P0) {
    __shared__ float hs[16 * 128];
    int block_row = blockIdx.x * 16;
    int tid = threadIdx.x;
    int c = tid & 127;
    int rg = tid >> 7;
    int y = blockIdx.y;
    for (int i = tid; i < 16 * 32; i += 256)
        ((float4*)hs)[i] = ((const float4*)(h + block_row * 128))[i];
    __syncthreads();
    float acc[8] = {0.f, 0.f, 0.f, 0.f, 0.f, 0.f, 0.f, 0.f};
    if (y == 0) {
        for (int k4 = 0; k4 < 32; k4++) {
            int k = 4 * k4;
            float w0 = WqT[k * 128 + c], w1 = WqT[(k + 1) * 128 + c];
            float w2 = WqT[(k + 2) * 128 + c], w3 = WqT[(k + 3) * 128 + c];
#pragma unroll
            for (int r = 0; r < 8; r++) {
                float4 h4 = *(const float4*)&hs[(rg + 2 * r) * 128 + k];
                acc[r] += h4.x * w0; acc[r] += h4.y * w1;
                acc[r] += h4.z * w2; acc[r] += h4.w * w3;
            }
        }
#pragma unroll
        for (int r = 0; r < 8; r++)
            Z[(block_row + rg + 2 * r) * 128 + c] = acc[r];
    } else {
        int col = (y - 1) * 128 + c;
        for (int k4 = 0; k4 < 32; k4++) {
            int k = 4 * k4;
            float w0 = Wih[k * 384 + col], w1 = Wih[(k + 1) * 384 + col];
            float w2 = Wih[(k + 2) * 384 + col], w3 = Wih[(k + 3) * 384 + col];
#pragma unroll
            for (int r = 0; r < 8; r++) {
                float4 h4 = *(const float4*)&hs[(rg + 2 * r) * 128 + k];
                acc[r] += h4.x * w0; acc[r] += h4.y * w1;
                acc[r] += h4.z * w2; acc[r] += h4.w * w3;
            }
        }
        float bb = bih[col];
#pragma unroll
        for (int r = 0; r < 8; r++)
            P0[(size_t)(block_row + rg + 2 * r) * 384 + col] = acc[r] + bb;
    }
}

// h' = relu(h@Ws + A@hw); 10 rows/block; float4 hs/As reads, ordered FMAs
__global__ void k_agg10(const float* __restrict__ h, const float* __restrict__ Ws,
                        const float* __restrict__ A, const float* __restrict__ hw,
                        float* __restrict__ out) {
    __shared__ float hs[10 * 128];
    __shared__ float As[10 * 100];
    int b = blockIdx.x / 10;
    int i0 = (blockIdx.x % 10) * 10;
    int tid = threadIdx.x;
    int col = tid & 127;
    int rg = tid >> 7;
    int rowbase = b * NN + i0;
    for (int i = tid; i < 10 * 32; i += 256)
        ((float4*)hs)[i] = ((const float4*)(h + rowbase * 128))[i];
    for (int i = tid; i < 10 * 25; i += 256)
        ((float4*)As)[i] = ((const float4*)(A + rowbase * 100))[i];
    __syncthreads();
    float acc[5] = {0.f, 0.f, 0.f, 0.f, 0.f};
    for (int k4 = 0; k4 < 32; k4++) {
        int k = 4 * k4;
        float w0 = Ws[k * 128 + col], w1 = Ws[(k + 1) * 128 + col];
        float w2 = Ws[(k + 2) * 128 + col], w3 = Ws[(k + 3) * 128 + col];
#pragma unroll
        for (int r = 0; r < 5; r++) {
            float4 h4 = *(const float4*)&hs[(rg + 2 * r) * 128 + k];
            acc[r] += h4.x * w0; acc[r] += h4.y * w1;
            acc[r] += h4.z * w2; acc[r] += h4.w * w3;
        }
    }
    const float* hwb = hw + b * NN * 128;
    for (int j4 = 0; j4 < 25; j4++) {
        int j = 4 * j4;
        float v0 = hwb[j * 128 + col], v1 = hwb[(j + 1) * 128 + col];
        float v2 = hwb[(j + 2) * 128 + col], v3 = hwb[(j + 3) * 128 + col];
#pragma unroll
        for (int r = 0; r < 5; r++) {
            float4 a4 = *(const float4*)&As[(rg + 2 * r) * 100 + j];
            acc[r] += a4.x * v0; acc[r] += a4.y * v1;
            acc[r] += a4.z * v2; acc[r] += a4.w * v3;
        }
    }
#pragma unroll
    for (int r = 0; r < 5; r++)
        out[(rowbase + rg + 2 * r) * 128 + col] = fmaxf(acc[r], 0.0f);
}

// ---------------- shared matvec tile (spill-proof, ~40 VGPR) ----------------
__device__ __forceinline__ void matvec_tile4(const float* __restrict__ W,   // &W[k0*384 + j0]
                                             const float* __restrict__ hp,  // &h[k0]; modes +0,+132
                                             int nk4,
                                             float* __restrict__ pg0,
                                             float* __restrict__ pg1) {
    float a00 = 0.f, a01 = 0.f, a02 = 0.f, a03 = 0.f;
    float a10 = 0.f, a11 = 0.f, a12 = 0.f, a13 = 0.f;
#pragma unroll 4
    for (int k4 = 0; k4 < nk4; ++k4) {
        float4 hA = *(const float4*)(hp + 4 * k4);
        float4 hB = *(const float4*)(hp + 132 + 4 * k4);
        const float* Wk = W + (size_t)(4 * k4) * T3;
        float4 w0 = *(const float4*)(Wk);
        float4 w1 = *(const float4*)(Wk + T3);
        float4 w2 = *(const float4*)(Wk + 2 * T3);
        float4 w3 = *(const float4*)(Wk + 3 * T3);
        a00 += hA.x * w0.x; a01 += hA.x * w0.y; a02 += hA.x * w0.z; a03 += hA.x * w0.w;
        a10 += hB.x * w0.x; a11 += hB.x * w0.y; a12 += hB.x * w0.z; a13 += hB.x * w0.w;
        a00 += hA.y * w1.x; a01 += hA.y * w1.y; a02 += hA.y * w1.z; a03 += hA.y * w1.w;
        a10 += hB.y * w1.x; a11 += hB.y * w1.y; a12 += hB.y * w1.z; a13 += hB.y * w1.w;
        a00 += hA.z * w2.x; a01 += hA.z * w2.y; a02 += hA.z * w2.z; a03 += hA.z * w2.w;
        a10 += hB.z * w2.x; a11 += hB.z * w2.y; a12 += hB.z * w2.z; a13 += hB.z * w2.w;
        a00 += hA.w * w3.x; a01 += hA.w * w3.y; a02 += hA.w * w3.z; a03 += hA.w * w3.w;
        a10 += hB.w * w3.x; a11 += hB.w * w3.y; a12 += hB.w * w3.z; a13 += hB.w * w3.w;
    }
    float4 o;
    o.x = a00; o.y = a01; o.z = a02; o.w = a03;
    *(float4*)pg0 = o;
    o.x = a10; o.y = a11; o.z = a12; o.w = a13;
    *(float4*)pg1 = o;
}

// LDS-slab variant: identical arithmetic, W points into LDS (ds_read_b128 path)
__device__ __forceinline__ void matvec_tile4_lds(const float* W, const float* hp, int nk4,
                                                 float* pg0, float* pg1) {
    float a00 = 0.f, a01 = 0.f, a02 = 0.f, a03 = 0.f;
    float a10 = 0.f, a11 = 0.f, a12 = 0.f, a13 = 0.f;
#pragma unroll 4
    for (int k4 = 0; k4 < nk4; ++k4) {
        float4 hA = *(const float4*)(hp + 4 * k4);
        float4 hB = *(const float4*)(hp + 132 + 4 * k4);
        const float* Wk = W + (size_t)(4 * k4) * T3;
        float4 w0 = *(const float4*)(Wk);
        float4 w1 = *(const float4*)(Wk + T3);
        float4 w2 = *(const float4*)(Wk + 2 * T3);
        float4 w3 = *(const float4*)(Wk + 3 * T3);
        a00 += hA.x * w0.x; a01 += hA.x * w0.y; a02 += hA.x * w0.z; a03 += hA.x * w0.w;
        a10 += hB.x * w0.x; a11 += hB.x * w0.y; a12 += hB.x * w0.z; a13 += hB.x * w0.w;
        a00 += hA.y * w1.x; a01 += hA.y * w1.y; a02 += hA.y * w1.z; a03 += hA.y * w1.w;
        a10 += hB.y * w1.x; a11 += hB.y * w1.y; a12 += hB.y * w1.z; a13 += hB.y * w1.w;
        a00 += hA.z * w2.x; a01 += hA.z * w2.y; a02 += hA.z * w2.z; a03 += hA.z * w2.w;
        a10 += hB.z * w2.x; a11 += hB.z * w2.y; a12 += hB.z * w2.z; a13 += hB.z * w2.w;
        a00 += hA.w * w3.x; a01 += hA.w * w3.y; a02 += hA.w * w3.z; a03 += hA.w * w3.w;
        a10 += hB.w * w3.x; a11 += hB.w * w3.y; a12 += hB.w * w3.z; a13 += hB.w * w3.w;
    }
    float4 o;
    o.x = a00; o.y = a01; o.z = a02; o.w = a03;
    *(float4*)pg0 = o;
    o.x = a10; o.y = a11; o.z = a12; o.w = a13;
    *(float4*)pg1 = o;
}

// ---------------- decoder v12: decode9 + 32-row Wih1 slab pinned in LDS ----------------
// The per-CU L2 fill ceiling (~34 B/cyc) makes step time = stream-bytes / rate.
// VGPR pinning is compiler-defeated (3 attempts); LDS cannot be. Pin Wih1 rows
// 0..31 (48 KB, the free LDS) once; phase C slices ksC<2 read the slab —
// bitwise-identical values and FMA order. Stream 590 -> 542 KB/step.
// Sentinels: LDS_Block_Size ~161 KB, WRITE ~37 KB, VGPR ~84.
__global__ __launch_bounds__(768, 3) void k_decode12(
    const float* __restrict__ P0,       // [6400, 384]  x@Wih0 + bih0
    const float* __restrict__ Z,        // [6400, 128]  x@Wq^T
    const float* __restrict__ dis,
    const float* __restrict__ Wih,      // [2,128,384]
    const float* __restrict__ Whh,      // [2,128,384]
    const float* __restrict__ bih,
    const float* __restrict__ bhh,
    float* __restrict__ out) {
    __shared__ float Zs[NN * 132];          // 52.8 KB
    __shared__ float wslab[32 * T3];        // 48 KB: Wih1 rows 0..31
    __shared__ float h0s[2 * 132], h1s[2 * 132];
    __shared__ float pgA[4 * 2 * 392];      // gh0 partials [ks4][m][392]
    __shared__ float pgB[4 * 2 * 392];      // gh1 partials
    __shared__ float pgC[8 * 2 * 392];      // gi1 partials [ks8][m][392]
    __shared__ float sbhh0[T3], sbih1[T3], sbhh1[T3];
    __shared__ float pl[2 * 2 * 100];       // [m][ks][n]
    __shared__ float gum[128];
    __shared__ int s_ind2[2];

    const int tid = threadIdx.x;
    const int b = blockIdx.x;

    const float* __restrict__ Wih1 = Wih + 128 * T3;

    // phase-A matvec role (all 768 threads)
    const int unitA = tid / 384;             // 0: Whh0*h0 -> pgA, 1: Whh1*h1 -> pgB
    const int rA = tid - unitA * 384;
    const int ksA = rA / 96, j4A = rA - ksA * 96;
    const int j0A = j4A * 4, k0A = ksA * 32;
    // phase-C matvec role
    const int ksC = tid / 96, j4C = tid - ksC * 96;
    const int j0C = j4C * 4, k0C = ksC * 16;

    // ---- static staging: Zs + Wih1 slab (rows 0..31 = first 3072 float4s) ----
    for (int i4 = tid; i4 < NN * 32; i4 += 768) {
        int r = i4 >> 5, c4 = (i4 & 31) * 4;
        *(float4*)&Zs[r * 132 + c4] = *(const float4*)&Z[(b * NN + r) * 128 + c4];
    }
    for (int i4 = tid; i4 < 32 * 96; i4 += 768)
        ((float4*)wslab)[i4] = ((const float4*)Wih1)[i4];
    if (tid < T3) {
        sbhh0[tid] = bhh[tid];
        sbih1[tid] = bih[T3 + tid];
        sbhh1[tid] = bhh[T3 + tid];
    }
    if (tid < 256) {
        int m = tid >> 7, i = tid & 127;
        h0s[m * 132 + i] = 0.0f;
        h1s[m * 132 + i] = 0.0f;
    }
    if (tid == 0) { s_ind2[0] = 0; s_ind2[1] = 0; }

    unsigned kk0, kk1;
    tf2x32(0u, 42u, 0u, 0u, kk0, kk1);   // k1 of split(key(42)); advanced uniformly below

    int lastm = 0;       // tracked by tid<128 (selection threads)
    float dist = 0.0f;
    __syncthreads();

    for (int t = 0; t < NN - 1; t++) {
        // ---- RNG chain advance (uniform in all threads) ----
        unsigned sk0, sk1, nkA, nkB;
        tf2x32(kk0, kk1, 0u, 1u, sk0, sk1);
        tf2x32(kk0, kk1, 0u, 0u, nkA, nkB);
        kk0 = nkA; kk1 = nkB;

        // ---- gi0 prefetch into registers (loads in flight during phase A) ----
        float pf_r = 0.f, pf_z = 0.f, pf_n = 0.f;
        if (tid < 256) {
            const float* P0row = P0 + (size_t)(b * NN + s_ind2[tid >> 7]) * T3;
            int i = tid & 127;
            pf_r = P0row[i];
            pf_z = P0row[i + 128];
            pf_n = P0row[i + 256];
        }

        // ===== phase A: gh0 & gh1 partials — all 768 threads stream Whh =====
        {
            const float* W = Whh + unitA * (128 * T3) + (size_t)k0A * T3 + j0A;
            const float* hp = ((unitA == 0) ? h0s : h1s) + k0A;
            float* pg = (unitA == 0) ? pgA : pgB;
            matvec_tile4(W, hp, 8,
                         &pg[(ksA * 2 + 0) * 392 + j0A],
                         &pg[(ksA * 2 + 1) * 392 + j0A]);
        }
        __syncthreads();

        // ===== phase B: h0 update (256 thr) + gumbel (thr 256..355) =====
        if (tid < 256) {
            int m = tid >> 7, i = tid & 127;
            float ghr = sbhh0[i], ghz = sbhh0[i + 128], ghn = sbhh0[i + 256];
#pragma unroll
            for (int ks = 0; ks < 4; ks++) {
                int pb = (ks * 2 + m) * 392;
                ghr += pgA[pb + i];
                ghz += pgA[pb + i + 128];
                ghn += pgA[pb + i + 256];
            }
            float rr = 1.0f / (1.0f + expf(-(pf_r + ghr)));
            float zz = 1.0f / (1.0f + expf(-(pf_z + ghz)));
            float nn = tanhf(pf_n + rr * ghn);
            h0s[m * 132 + i] = (1.0f - zz) * nn + zz * h0s[m * 132 + i];
        } else if (tid < 356) {
            int u = tid - 256;
            gum[u] = gumbel_f(sk0, sk1, (unsigned)(b * NN + u));
        }
        __syncthreads();

        // ===== phase C: gi1 partials — slab rows (ksC<2) from LDS, rest global =====
        if (ksC < 2) {
            matvec_tile4_lds(&wslab[(size_t)k0C * T3 + j0C], h0s + k0C, 4,
                             &pgC[(ksC * 2 + 0) * 392 + j0C],
                             &pgC[(ksC * 2 + 1) * 392 + j0C]);
        } else {
            matvec_tile4(Wih1 + (size_t)k0C * T3 + j0C, h0s + k0C, 4,
                         &pgC[(ksC * 2 + 0) * 392 + j0C],
                         &pgC[(ksC * 2 + 1) * 392 + j0C]);
        }
        __syncthreads();

        // ===== phase D: h1 update (256 thr) =====
        if (tid < 256) {
            int m = tid >> 7, i = tid & 127;
            float gir = sbih1[i], giz = sbih1[i + 128], gin = sbih1[i + 256];
#pragma unroll
            for (int ks = 0; ks < 8; ks++) {
                int pb = (ks * 2 + m) * 392;
                gir += pgC[pb + i];
                giz += pgC[pb + i + 128];
                gin += pgC[pb + i + 256];
            }
            float ghr = sbhh1[i], ghz = sbhh1[i + 128], ghn = sbhh1[i + 256];
#pragma unroll
            for (int ks = 0; ks < 4; ks++) {
                int pb = (ks * 2 + m) * 392;
                ghr += pgB[pb + i];
                ghz += pgB[pb + i + 128];
                ghn += pgB[pb + i + 256];
            }
            float rr = 1.0f / (1.0f + expf(-(gir + ghr)));
            float zz = 1.0f / (1.0f + expf(-(giz + ghz)));
            float nn = tanhf(gin + rr * ghn);
            h1s[m * 132 + i] = (1.0f - zz) * nn + zz * h1s[m * 132 + i];
        }
        __syncthreads();

        // ===== phase E: logits partials (200 thr) =====
        if (tid < 200) {
            int ks = tid / 100, n = tid - ks * 100;
            int kk0p = ks * 64;
            const float* Zp = &Zs[n * 132 + kk0p];
            const float* hp = &h1s[kk0p];
            float a0 = 0.f, a1 = 0.f;
#pragma unroll 4
            for (int q = 0; q < 16; q++) {
                float4 z4 = *(const float4*)(Zp + 4 * q);
                float4 hA = *(const float4*)(hp + 4 * q);
                float4 hB = *(const float4*)(hp + 132 + 4 * q);
                a0 += hA.x * z4.x; a0 += hA.y * z4.y; a0 += hA.z * z4.z; a0 += hA.w * z4.w;
                a1 += hB.x * z4.x; a1 += hB.y * z4.y; a1 += hB.z * z4.z; a1 += hB.w * z4.w;
            }
            pl[(0 * 2 + ks) * 100 + n] = a0;
            pl[(1 * 2 + ks) * 100 + n] = a1;
        }
        __syncthreads();

        // ===== phase F: softmax stats + selection (wave0: sample, wave1: greedy) =====
        if (tid < 128) {
            const int m = tid >> 6, lane = tid & 63;
            float v0, v1 = -__builtin_inff();
            v0 = (pl[(m * 2 + 0) * 100 + lane] + pl[(m * 2 + 1) * 100 + lane]) * SCALEF;
            if (lane + 64 < NN)
                v1 = (pl[(m * 2 + 0) * 100 + lane + 64] + pl[(m * 2 + 1) * 100 + lane + 64]) * SCALEF;
            float mx = fmaxf(v0, v1);
            for (int off = 32; off > 0; off >>= 1) mx = fmaxf(mx, __shfl_xor(mx, off));
            float e = expf(v0 - mx) + ((lane + 64 < NN) ? expf(v1 - mx) : 0.0f);
            for (int off = 32; off > 0; off >>= 1) e += __shfl_xor(e, off);
            float a0 = v0, a1 = v1;
            if (m == 0) {
                a0 += gum[lane];
                if (lane + 64 < NN) a1 += gum[lane + 64];
            }
            float bv; int bi;
            if (a1 > a0) { bv = a1; bi = lane + 64; } else { bv = a0; bi = lane; }
            for (int off = 32; off > 0; off >>= 1) {
                float ov = __shfl_xor(bv, off);
                int   oi = __shfl_xor(bi, off);
                if (ov > bv || (ov == bv && oi < bi)) { bv = ov; bi = oi; }
            }
            int ind = bi;
            float la = __shfl(v0, ind & 63);
            float lb = __shfl(v1, ind & 63);
            float lv = (ind < 64) ? la : lb;
            if (lane == 0) {
                if (m == 0) out[O0 + b * (NN - 1) + t] = lv - mx - logf(e);
                else        out[O4 + (size_t)b * NN * NN + lastm * NN + ind] = 1.0f;
                s_ind2[m] = ind;
            }
            dist += dis[b * NN * NN + lastm * NN + ind];
            lastm = ind;
        }
        __syncthreads();
    }

    if (tid == 0)  out[O1 + b] = dist;
    if (tid == 64) out[O2 + b] = dist;
}

// ---------------- host launcher ----------------
extern "C" void kernel_launch(void* const* d_in, const int* in_sizes, int n_in,
                              void* d_out, int out_size, void* d_ws, size_t ws_size,
                              hipStream_t stream) {
    (void)in_sizes; (void)n_in; (void)out_size; (void)ws_size;
    const float* node   = (const float*)d_in[0];
    const float* demand = (const float*)d_in[1];
    const float* dis    = (const float*)d_in[2];
    const float* Wn0    = (const float*)d_in[3];
    const float* bn0    = (const float*)d_in[4];
    const float* Ws     = (const float*)d_in[5];
    const float* Wngh   = (const float*)d_in[6];
    const float* We     = (const float*)d_in[7];
    const float* be     = (const float*)d_in[8];
    const float* Wih    = (const float*)d_in[9];
    const float* Whh    = (const float*)d_in[10];
    const float* bih    = (const float*)d_in[11];
    const float* bhh    = (const float*)d_in[12];
    const float* Wq     = (const float*)d_in[13];
    const float* Wc     = (const float*)d_in[14];
    const float* bc     = (const float*)d_in[15];
    float* out = (float*)d_out;
    float* ws  = (float*)d_ws;

    float* hA  = ws;                // 819200
    float* hB  = ws + 819200;       // 819200
    float* hw  = ws + 1638400;      // hw during encoder; Z after
    float* A   = ws + 2457600;      // A during encoder
    float* P0  = ws + 2457600;      // P0 overlays A after encoder
    float* WqT = ws + 4915200;      // 16384

    // fused: embed + adj + Wq transpose + predict + zero (all independent parts)
    hipLaunchKernelGGL(k_pre0, dim3(6739), dim3(256), 0, stream,
                       node, demand, Wn0, bn0, dis, We, be, Wc, bc, Wq,
                       hA, A, WqT, out + O3, out + O4);

    float* cur = hA;
    float* nxt = hB;
    for (int l = 0; l < 3; l++) {
        hipLaunchKernelGGL(k_hw16, dim3(400), dim3(256), 0, stream, cur, Wngh + l * 16384, hw);
        hipLaunchKernelGGL(k_agg10, dim3(640), dim3(256), 0, stream, cur, Ws + l * 16384, A, hw, nxt);
        float* tswap = cur; cur = nxt; nxt = tswap;
    }
    // cur == hB holds the final encoder output

    hipLaunchKernelGGL(k_zp, dim3(400, 4), dim3(256), 0, stream, cur, WqT, Wih, bih, hw, P0);

    hipLaunchKernelGGL(k_decode12, dim3(64), dim3(768), 0, stream,
                       P0, hw, dis, Wih, Whh, bih, bhh, out);
}

// Round 14
// 912.063 us; speedup vs baseline: 1.0753x; 1.0753x over previous
//
#include <hip/hip_runtime.h>
#include <math.h>

// Problem constants
#define BB 64
#define NN 100
#define HH 128
#define T3 384

// Output layout (floats, concatenated in return order)
#define O0 0            // sample_logprob [64,99]
#define O1 6336         // sample_distance [64,1]
#define O2 6400         // greedy_distance [64,1]
#define O3 6464         // predict_matrix [64,100,100,2]
#define O4 1286464      // greedy_solution_matrix [64,100,100]

#define TINYF 1.17549435e-38f
#define SCALEF 0.08838834764831845f

// ---------------- threefry2x32 (exact JAX implementation) ----------------
__device__ __forceinline__ unsigned rotl32(unsigned x, int d) {
    return (x << d) | (x >> (32 - d));
}

__device__ __forceinline__ void tf2x32(unsigned ks0, unsigned ks1,
                                       unsigned x0, unsigned x1,
                                       unsigned& o0, unsigned& o1) {
    unsigned ks2 = ks0 ^ ks1 ^ 0x1BD11BDAu;
    x0 += ks0; x1 += ks1;
    x0 += x1; x1 = rotl32(x1, 13); x1 ^= x0;
    x0 += x1; x1 = rotl32(x1, 15); x1 ^= x0;
    x0 += x1; x1 = rotl32(x1, 26); x1 ^= x0;
    x0 += x1; x1 = rotl32(x1, 6);  x1 ^= x0;
    x0 += ks1; x1 += ks2 + 1u;
    x0 += x1; x1 = rotl32(x1, 17); x1 ^= x0;
    x0 += x1; x1 = rotl32(x1, 29); x1 ^= x0;
    x0 += x1; x1 = rotl32(x1, 16); x1 ^= x0;
    x0 += x1; x1 = rotl32(x1, 24); x1 ^= x0;
    x0 += ks2; x1 += ks0 + 2u;
    x0 += x1; x1 = rotl32(x1, 13); x1 ^= x0;
    x0 += x1; x1 = rotl32(x1, 15); x1 ^= x0;
    x0 += x1; x1 = rotl32(x1, 26); x1 ^= x0;
    x0 += x1; x1 = rotl32(x1, 6);  x1 ^= x0;
    x0 += ks0; x1 += ks1 + 3u;
    x0 += x1; x1 = rotl32(x1, 17); x1 ^= x0;
    x0 += x1; x1 = rotl32(x1, 29); x1 ^= x0;
    x0 += x1; x1 = rotl32(x1, 16); x1 ^= x0;
    x0 += x1; x1 = rotl32(x1, 24); x1 ^= x0;
    x0 += ks1; x1 += ks2 + 4u;
    x0 += x1; x1 = rotl32(x1, 13); x1 ^= x0;
    x0 += x1; x1 = rotl32(x1, 15); x1 ^= x0;
    x0 += x1; x1 = rotl32(x1, 26); x1 ^= x0;
    x0 += x1; x1 = rotl32(x1, 6);  x1 ^= x0;
    x0 += ks2; x1 += ks0 + 5u;
    o0 = x0; o1 = x1;
}

__device__ __forceinline__ float gumbel_f(unsigned k0, unsigned k1, unsigned f) {
    unsigned o0, o1;
    tf2x32(k0, k1, 0u, f, o0, o1);
    unsigned bits = o0 ^ o1;
    float u01 = __uint_as_float((bits >> 9) | 0x3F800000u) - 1.0f;
    float u = fmaxf(TINYF, u01 * (1.0f - TINYF) + TINYF);
    return -logf(-logf(u));
}

// ---------------- fused pre-kernel: embed + adj + transpose + predict + zero ----------
__global__ void k_pre0(const float* __restrict__ node, const float* __restrict__ demand,
                       const float* __restrict__ Wn0, const float* __restrict__ bn0,
                       const float* __restrict__ dis,
                       const float* __restrict__ We, const float* __restrict__ be,
                       const float* __restrict__ Wc, const float* __restrict__ bc,
                       const float* __restrict__ Wq,
                       float* __restrict__ h, float* __restrict__ A,
                       float* __restrict__ WqT,
                       float* __restrict__ out3, float* __restrict__ zp) {
    __shared__ float sWe[128], sbe[128], sc0[128], sc1[128];
    int bid = blockIdx.x, tid = threadIdx.x;
    if (bid < 3200) {
        int idx = bid * 256 + tid;
        int r = idx >> 7, c = idx & 127;
        float v = node[r * 2] * Wn0[c] + node[r * 2 + 1] * Wn0[128 + c]
                + demand[r] * Wn0[256 + c] + bn0[c];
        h[idx] = fmaxf(v, 0.0f);
    } else if (bid < 4800) {
        int row = (bid - 3200) * 4 + (tid >> 6);
        int l = tid & 63;
        const float* d = dis + row * NN;
        float v0 = -d[l];
        float v1 = (l + 64 < NN) ? -d[l + 64] : -__builtin_inff();
        float m = fmaxf(v0, v1);
        for (int off = 32; off > 0; off >>= 1) m = fmaxf(m, __shfl_xor(m, off));
        float e0 = expf(v0 - m);
        float e1 = (l + 64 < NN) ? expf(v1 - m) : 0.0f;
        float s = e0 + e1;
        for (int off = 32; off > 0; off >>= 1) s += __shfl_xor(s, off);
        float inv = 1.0f / s;
        A[row * NN + l] = e0 * inv;
        if (l + 64 < NN) A[row * NN + l + 64] = e1 * inv;
    } else if (bid < 4864) {
        int i = (bid - 4800) * 256 + tid;
        int k = i >> 7, c = i & 127;
        WqT[k * 128 + c] = Wq[c * 128 + k];
    } else if (bid < 6114) {
        if (tid < 128) {
            sWe[tid] = We[tid];
            sbe[tid] = be[tid];
            sc0[tid] = Wc[tid * 2];
            sc1[tid] = Wc[tid * 2 + 1];
        }
        __syncthreads();
        float b0 = bc[0], b1 = bc[1];
        int p0 = (bid - 4864) * 512 + tid, p1 = p0 + 256;
        float d0 = dis[p0], d1 = dis[p1];
        float a00 = b0, a01 = b1, a10 = b0, a11 = b1;
        for (int k4 = 0; k4 < 32; k4++) {
            float4 we = *(const float4*)&sWe[4 * k4];
            float4 bb = *(const float4*)&sbe[4 * k4];
            float4 c0 = *(const float4*)&sc0[4 * k4];
            float4 c1 = *(const float4*)&sc1[4 * k4];
            float e0, e1;
            e0 = fmaxf(d0 * we.x + bb.x, 0.0f); a00 += e0 * c0.x; a01 += e0 * c1.x;
            e1 = fmaxf(d1 * we.x + bb.x, 0.0f); a10 += e1 * c0.x; a11 += e1 * c1.x;
            e0 = fmaxf(d0 * we.y + bb.y, 0.0f); a00 += e0 * c0.y; a01 += e0 * c1.y;
            e1 = fmaxf(d1 * we.y + bb.y, 0.0f); a10 += e1 * c0.y; a11 += e1 * c1.y;
            e0 = fmaxf(d0 * we.z + bb.z, 0.0f); a00 += e0 * c0.z; a01 += e0 * c1.z;
            e1 = fmaxf(d1 * we.z + bb.z, 0.0f); a10 += e1 * c0.z; a11 += e1 * c1.z;
            e0 = fmaxf(d0 * we.w + bb.w, 0.0f); a00 += e0 * c0.w; a01 += e0 * c1.w;
            e1 = fmaxf(d1 * we.w + bb.w, 0.0f); a10 += e1 * c0.w; a11 += e1 * c1.w;
        }
        {
            float m = fmaxf(a00, a01);
            float q0 = expf(a00 - m), q1 = expf(a01 - m);
            float inv = 1.0f / (q0 + q1);
            out3[p0 * 2] = q0 * inv;
            out3[p0 * 2 + 1] = q1 * inv;
        }
        {
            float m = fmaxf(a10, a11);
            float q0 = expf(a10 - m), q1 = expf(a11 - m);
            float inv = 1.0f / (q0 + q1);
            out3[p1 * 2] = q0 * inv;
            out3[p1 * 2 + 1] = q1 * inv;
        }
    } else {
        int i = (bid - 6114) * 256 + tid;
        float4 z; z.x = 0.f; z.y = 0.f; z.z = 0.f; z.w = 0.f;
        ((float4*)zp)[i] = z;
    }
}

// out[6400x128] = h @ W[128x128]; 16 rows/block; float4 h reads, ordered FMAs
__global__ void k_hw16(const float* __restrict__ h, const float* __restrict__ W,
                       float* __restrict__ out) {
    __shared__ float hs[16 * 128];
    int block_row = blockIdx.x * 16;
    int tid = threadIdx.x;
    int col = tid & 127;
    int rg = tid >> 7;
    for (int i = tid; i < 16 * 32; i += 256)
        ((float4*)hs)[i] = ((const float4*)(h + block_row * 128))[i];
    __syncthreads();
    float acc[8] = {0.f, 0.f, 0.f, 0.f, 0.f, 0.f, 0.f, 0.f};
    for (int k4 = 0; k4 < 32; k4++) {
        int k = 4 * k4;
        float w0 = W[k * 128 + col], w1 = W[(k + 1) * 128 + col];
        float w2 = W[(k + 2) * 128 + col], w3 = W[(k + 3) * 128 + col];
#pragma unroll
        for (int r = 0; r < 8; r++) {
            float4 h4 = *(const float4*)&hs[(rg + 2 * r) * 128 + k];
            acc[r] += h4.x * w0; acc[r] += h4.y * w1;
            acc[r] += h4.z * w2; acc[r] += h4.w * w3;
        }
    }
#pragma unroll
    for (int r = 0; r < 8; r++)
        out[(block_row + rg + 2 * r) * 128 + col] = acc[r];
}

// fused Z (h@WqT) + P0 (h@Wih0+bih0); grid (400, 4); float4 h reads
__global__ void k_zp(const float* __restrict__ h, const float* __restrict__ WqT,
                     const float* __restrict__ Wih, const float* __restrict__ bih,
                     float* __restrict__ Z, float* __restrict__ P0) {
    __shared__ float hs[16 * 128];
    int block_row = blockIdx.x * 16;
    int tid = threadIdx.x;
    int c = tid & 127;
    int rg = tid >> 7;
    int y = blockIdx.y;
    for (int i = tid; i < 16 * 32; i += 256)
        ((float4*)hs)[i] = ((const float4*)(h + block_row * 128))[i];
    __syncthreads();
    float acc[8] = {0.f, 0.f, 0.f, 0.f, 0.f, 0.f, 0.f, 0.f};
    if (y == 0) {
        for (int k4 = 0; k4 < 32; k4++) {
            int k = 4 * k4;
            float w0 = WqT[k * 128 + c], w1 = WqT[(k + 1) * 128 + c];
            float w2 = WqT[(k + 2) * 128 + c], w3 = WqT[(k + 3) * 128 + c];
#pragma unroll
            for (int r = 0; r < 8; r++) {
                float4 h4 = *(const float4*)&hs[(rg + 2 * r) * 128 + k];
                acc[r] += h4.x * w0; acc[r] += h4.y * w1;
                acc[r] += h4.z * w2; acc[r] += h4.w * w3;
            }
        }
#pragma unroll
        for (int r = 0; r < 8; r++)
            Z[(block_row + rg + 2 * r) * 128 + c] = acc[r];
    } else {
        int col = (y - 1) * 128 + c;
        for (int k4 = 0; k4 < 32; k4++) {
            int k = 4 * k4;
            float w0 = Wih[k * 384 + col], w1 = Wih[(k + 1) * 384 + col];
            float w2 = Wih[(k + 2) * 384 + col], w3 = Wih[(k + 3) * 384 + col];
#pragma unroll
            for (int r = 0; r < 8; r++) {
                float4 h4 = *(const float4*)&hs[(rg + 2 * r) * 128 + k];
                acc[r] += h4.x * w0; acc[r] += h4.y * w1;
                acc[r] += h4.z * w2; acc[r] += h4.w * w3;
            }
        }
        float bb = bih[col];
#pragma unroll
        for (int r = 0; r < 8; r++)
            P0[(size_t)(block_row + rg + 2 * r) * 384 + col] = acc[r] + bb;
    }
}

// h' = relu(h@Ws + A@hw); 10 rows/block; float4 hs/As reads, ordered FMAs
__global__ void k_agg10(const float* __restrict__ h, const float* __restrict__ Ws,
                        const float* __restrict__ A, const float* __restrict__ hw,
                        float* __restrict__ out) {
    __shared__ float hs[10 * 128];
    __shared__ float As[10 * 100];
    int b = blockIdx.x / 10;
    int i0 = (blockIdx.x % 10) * 10;
    int tid = threadIdx.x;
    int col = tid & 127;
    int rg = tid >> 7;
    int rowbase = b * NN + i0;
    for (int i = tid; i < 10 * 32; i += 256)
        ((float4*)hs)[i] = ((const float4*)(h + rowbase * 128))[i];
    for (int i = tid; i < 10 * 25; i += 256)
        ((float4*)As)[i] = ((const float4*)(A + rowbase * 100))[i];
    __syncthreads();
    float acc[5] = {0.f, 0.f, 0.f, 0.f, 0.f};
    for (int k4 = 0; k4 < 32; k4++) {
        int k = 4 * k4;
        float w0 = Ws[k * 128 + col], w1 = Ws[(k + 1) * 128 + col];
        float w2 = Ws[(k + 2) * 128 + col], w3 = Ws[(k + 3) * 128 + col];
#pragma unroll
        for (int r = 0; r < 5; r++) {
            float4 h4 = *(const float4*)&hs[(rg + 2 * r) * 128 + k];
            acc[r] += h4.x * w0; acc[r] += h4.y * w1;
            acc[r] += h4.z * w2; acc[r] += h4.w * w3;
        }
    }
    const float* hwb = hw + b * NN * 128;
    for (int j4 = 0; j4 < 25; j4++) {
        int j = 4 * j4;
        float v0 = hwb[j * 128 + col], v1 = hwb[(j + 1) * 128 + col];
        float v2 = hwb[(j + 2) * 128 + col], v3 = hwb[(j + 3) * 128 + col];
#pragma unroll
        for (int r = 0; r < 5; r++) {
            float4 a4 = *(const float4*)&As[(rg + 2 * r) * 100 + j];
            acc[r] += a4.x * v0; acc[r] += a4.y * v1;
            acc[r] += a4.z * v2; acc[r] += a4.w * v3;
        }
    }
#pragma unroll
    for (int r = 0; r < 5; r++)
        out[(rowbase + rg + 2 * r) * 128 + col] = fmaxf(acc[r], 0.0f);
}

// ---------------- shared matvec tile (spill-proof, ~40 VGPR) ----------------
__device__ __forceinline__ void matvec_tile4(const float* __restrict__ W,   // &W[k0*384 + j0]
                                             const float* __restrict__ hp,  // &h[k0]; modes +0,+132
                                             int nk4,
                                             float* __restrict__ pg0,
                                             float* __restrict__ pg1) {
    float a00 = 0.f, a01 = 0.f, a02 = 0.f, a03 = 0.f;
    float a10 = 0.f, a11 = 0.f, a12 = 0.f, a13 = 0.f;
#pragma unroll 4
    for (int k4 = 0; k4 < nk4; ++k4) {
        float4 hA = *(const float4*)(hp + 4 * k4);
        float4 hB = *(const float4*)(hp + 132 + 4 * k4);
        const float* Wk = W + (size_t)(4 * k4) * T3;
        float4 w0 = *(const float4*)(Wk);
        float4 w1 = *(const float4*)(Wk + T3);
        float4 w2 = *(const float4*)(Wk + 2 * T3);
        float4 w3 = *(const float4*)(Wk + 3 * T3);
        a00 += hA.x * w0.x; a01 += hA.x * w0.y; a02 += hA.x * w0.z; a03 += hA.x * w0.w;
        a10 += hB.x * w0.x; a11 += hB.x * w0.y; a12 += hB.x * w0.z; a13 += hB.x * w0.w;
        a00 += hA.y * w1.x; a01 += hA.y * w1.y; a02 += hA.y * w1.z; a03 += hA.y * w1.w;
        a10 += hB.y * w1.x; a11 += hB.y * w1.y; a12 += hB.y * w1.z; a13 += hB.y * w1.w;
        a00 += hA.z * w2.x; a01 += hA.z * w2.y; a02 += hA.z * w2.z; a03 += hA.z * w2.w;
        a10 += hB.z * w2.x; a11 += hB.z * w2.y; a12 += hB.z * w2.z; a13 += hB.z * w2.w;
        a00 += hA.w * w3.x; a01 += hA.w * w3.y; a02 += hA.w * w3.z; a03 += hA.w * w3.w;
        a10 += hB.w * w3.x; a11 += hB.w * w3.y; a12 += hB.w * w3.z; a13 += hB.w * w3.w;
    }
    float4 o;
    o.x = a00; o.y = a01; o.z = a02; o.w = a03;
    *(float4*)pg0 = o;
    o.x = a10; o.y = a11; o.z = a12; o.w = a13;
    *(float4*)pg1 = o;
}

// ---------------- decoder v11 (best measured: ~717 us, VGPR 84, no spill) ----------------
__global__ __launch_bounds__(768, 3) void k_decode11(
    const float* __restrict__ P0,       // [6400, 384]  x@Wih0 + bih0
    const float* __restrict__ Z,        // [6400, 128]  x@Wq^T
    const float* __restrict__ dis,
    const float* __restrict__ Wih,      // [2,128,384]
    const float* __restrict__ Whh,      // [2,128,384]
    const float* __restrict__ bih,
    const float* __restrict__ bhh,
    float* __restrict__ out) {
    __shared__ float Zs[NN * 132];          // 52.8 KB
    __shared__ float h0s[2 * 132], h1s[2 * 132];
    __shared__ float pgA[4 * 2 * 392];      // gh0 partials [ks4][m][392]
    __shared__ float pgB[4 * 2 * 392];      // gh1 partials
    __shared__ float pgC[8 * 2 * 392];      // gi1 partials [ks8][m][392]
    __shared__ float sbhh0[T3], sbih1[T3], sbhh1[T3];
    __shared__ float pl[2 * 2 * 100];       // [m][ks][n]
    __shared__ float gum[128];
    __shared__ int s_ind2[2];

    const int tid = threadIdx.x;
    const int b = blockIdx.x;

    const float* __restrict__ Wih1 = Wih + 128 * T3;

    // phase-A matvec role (all 768 threads)
    const int unitA = tid / 384;             // 0: Whh0*h0 -> pgA, 1: Whh1*h1 -> pgB
    const int rA = tid - unitA * 384;
    const int ksA = rA / 96, j4A = rA - ksA * 96;
    const int j0A = j4A * 4, k0A = ksA * 32;
    // phase-C matvec role
    const int ksC = tid / 96, j4C = tid - ksC * 96;
    const int j0C = j4C * 4, k0C = ksC * 16;

    // ---- static staging ----
    for (int i4 = tid; i4 < NN * 32; i4 += 768) {
        int r = i4 >> 5, c4 = (i4 & 31) * 4;
        *(float4*)&Zs[r * 132 + c4] = *(const float4*)&Z[(b * NN + r) * 128 + c4];
    }
    if (tid < T3) {
        sbhh0[tid] = bhh[tid];
        sbih1[tid] = bih[T3 + tid];
        sbhh1[tid] = bhh[T3 + tid];
    }
    if (tid < 256) {
        int m = tid >> 7, i = tid & 127;
        h0s[m * 132 + i] = 0.0f;
        h1s[m * 132 + i] = 0.0f;
    }
    if (tid == 0) { s_ind2[0] = 0; s_ind2[1] = 0; }

    unsigned kk0, kk1;
    tf2x32(0u, 42u, 0u, 0u, kk0, kk1);   // k1 of split(key(42)); advanced uniformly below

    int lastm = 0;       // tracked by tid<128 (selection threads)
    float dist = 0.0f;
    __syncthreads();

    for (int t = 0; t < NN - 1; t++) {
        // ---- RNG chain advance (uniform in all threads) ----
        unsigned sk0, sk1, nkA, nkB;
        tf2x32(kk0, kk1, 0u, 1u, sk0, sk1);
        tf2x32(kk0, kk1, 0u, 0u, nkA, nkB);
        kk0 = nkA; kk1 = nkB;

        // ---- gi0 prefetch into registers (loads in flight during phase A) ----
        float pf_r = 0.f, pf_z = 0.f, pf_n = 0.f;
        if (tid < 256) {
            const float* P0row = P0 + (size_t)(b * NN + s_ind2[tid >> 7]) * T3;
            int i = tid & 127;
            pf_r = P0row[i];
            pf_z = P0row[i + 128];
            pf_n = P0row[i + 256];
        }

        // ===== phase A: gh0 & gh1 partials — all 768 threads stream Whh =====
        {
            const float* W = Whh + unitA * (128 * T3) + (size_t)k0A * T3 + j0A;
            const float* hp = ((unitA == 0) ? h0s : h1s) + k0A;
            float* pg = (unitA == 0) ? pgA : pgB;
            matvec_tile4(W, hp, 8,
                         &pg[(ksA * 2 + 0) * 392 + j0A],
                         &pg[(ksA * 2 + 1) * 392 + j0A]);
        }
        __syncthreads();

        // ===== phase B: h0 update (256 thr) + gumbel (thr 256..355) =====
        if (tid < 256) {
            int m = tid >> 7, i = tid & 127;
            float ghr = sbhh0[i], ghz = sbhh0[i + 128], ghn = sbhh0[i + 256];
#pragma unroll
            for (int ks = 0; ks < 4; ks++) {
                int pb = (ks * 2 + m) * 392;
                ghr += pgA[pb + i];
                ghz += pgA[pb + i + 128];
                ghn += pgA[pb + i + 256];
            }
            float rr = 1.0f / (1.0f + expf(-(pf_r + ghr)));
            float zz = 1.0f / (1.0f + expf(-(pf_z + ghz)));
            float nn = tanhf(pf_n + rr * ghn);
            h0s[m * 132 + i] = (1.0f - zz) * nn + zz * h0s[m * 132 + i];
        } else if (tid < 356) {
            int u = tid - 256;
            gum[u] = gumbel_f(sk0, sk1, (unsigned)(b * NN + u));
        }
        __syncthreads();

        // ===== phase C: gi1 partials — all 768 threads stream Wih1 =====
        {
            const float* W = Wih1 + (size_t)k0C * T3 + j0C;
            matvec_tile4(W, h0s + k0C, 4,
                         &pgC[(ksC * 2 + 0) * 392 + j0C],
                         &pgC[(ksC * 2 + 1) * 392 + j0C]);
        }
        __syncthreads();

        // ===== phase D: h1 update (256 thr) =====
        if (tid < 256) {
            int m = tid >> 7, i = tid & 127;
            float gir = sbih1[i], giz = sbih1[i + 128], gin = sbih1[i + 256];
#pragma unroll
            for (int ks = 0; ks < 8; ks++) {
                int pb = (ks * 2 + m) * 392;
                gir += pgC[pb + i];
                giz += pgC[pb + i + 128];
                gin += pgC[pb + i + 256];
            }
            float ghr = sbhh1[i], ghz = sbhh1[i + 128], ghn = sbhh1[i + 256];
#pragma unroll
            for (int ks = 0; ks < 4; ks++) {
                int pb = (ks * 2 + m) * 392;
                ghr += pgB[pb + i];
                ghz += pgB[pb + i + 128];
                ghn += pgB[pb + i + 256];
            }
            float rr = 1.0f / (1.0f + expf(-(gir + ghr)));
            float zz = 1.0f / (1.0f + expf(-(giz + ghz)));
            float nn = tanhf(gin + rr * ghn);
            h1s[m * 132 + i] = (1.0f - zz) * nn + zz * h1s[m * 132 + i];
        }
        __syncthreads();

        // ===== phase E: logits partials (200 thr) =====
        if (tid < 200) {
            int ks = tid / 100, n = tid - ks * 100;
            int kk0p = ks * 64;
            const float* Zp = &Zs[n * 132 + kk0p];
            const float* hp = &h1s[kk0p];
            float a0 = 0.f, a1 = 0.f;
#pragma unroll 4
            for (int q = 0; q < 16; q++) {
                float4 z4 = *(const float4*)(Zp + 4 * q);
                float4 hA = *(const float4*)(hp + 4 * q);
                float4 hB = *(const float4*)(hp + 132 + 4 * q);
                a0 += hA.x * z4.x; a0 += hA.y * z4.y; a0 += hA.z * z4.z; a0 += hA.w * z4.w;
                a1 += hB.x * z4.x; a1 += hB.y * z4.y; a1 += hB.z * z4.z; a1 += hB.w * z4.w;
            }
            pl[(0 * 2 + ks) * 100 + n] = a0;
            pl[(1 * 2 + ks) * 100 + n] = a1;
        }
        __syncthreads();

        // ===== phase F: softmax stats + selection (wave0: sample, wave1: greedy) =====
        if (tid < 128) {
            const int m = tid >> 6, lane = tid & 63;
            float v0, v1 = -__builtin_inff();
            v0 = (pl[(m * 2 + 0) * 100 + lane] + pl[(m * 2 + 1) * 100 + lane]) * SCALEF;
            if (lane + 64 < NN)
                v1 = (pl[(m * 2 + 0) * 100 + lane + 64] + pl[(m * 2 + 1) * 100 + lane + 64]) * SCALEF;
            float mx = fmaxf(v0, v1);
            for (int off = 32; off > 0; off >>= 1) mx = fmaxf(mx, __shfl_xor(mx, off));
            float e = expf(v0 - mx) + ((lane + 64 < NN) ? expf(v1 - mx) : 0.0f);
            for (int off = 32; off > 0; off >>= 1) e += __shfl_xor(e, off);
            float a0 = v0, a1 = v1;
            if (m == 0) {
                a0 += gum[lane];
                if (lane + 64 < NN) a1 += gum[lane + 64];
            }
            float bv; int bi;
            if (a1 > a0) { bv = a1; bi = lane + 64; } else { bv = a0; bi = lane; }
            for (int off = 32; off > 0; off >>= 1) {
                float ov = __shfl_xor(bv, off);
                int   oi = __shfl_xor(bi, off);
                if (ov > bv || (ov == bv && oi < bi)) { bv = ov; bi = oi; }
            }
            int ind = bi;
            float la = __shfl(v0, ind & 63);
            float lb = __shfl(v1, ind & 63);
            float lv = (ind < 64) ? la : lb;
            if (lane == 0) {
                if (m == 0) out[O0 + b * (NN - 1) + t] = lv - mx - logf(e);
                else        out[O4 + (size_t)b * NN * NN + lastm * NN + ind] = 1.0f;
                s_ind2[m] = ind;
            }
            dist += dis[b * NN * NN + lastm * NN + ind];
            lastm = ind;
        }
        __syncthreads();
    }

    if (tid == 0)  out[O1 + b] = dist;
    if (tid == 64) out[O2 + b] = dist;
}

// ---------------- host launcher ----------------
extern "C" void kernel_launch(void* const* d_in, const int* in_sizes, int n_in,
                              void* d_out, int out_size, void* d_ws, size_t ws_size,
                              hipStream_t stream) {
    (void)in_sizes; (void)n_in; (void)out_size; (void)ws_size;
    const float* node   = (const float*)d_in[0];
    const float* demand = (const float*)d_in[1];
    const float* dis    = (const float*)d_in[2];
    const float* Wn0    = (const float*)d_in[3];
    const float* bn0    = (const float*)d_in[4];
    const float* Ws     = (const float*)d_in[5];
    const float* Wngh   = (const float*)d_in[6];
    const float* We     = (const float*)d_in[7];
    const float* be     = (const float*)d_in[8];
    const float* Wih    = (const float*)d_in[9];
    const float* Whh    = (const float*)d_in[10];
    const float* bih    = (const float*)d_in[11];
    const float* bhh    = (const float*)d_in[12];
    const float* Wq     = (const float*)d_in[13];
    const float* Wc     = (const float*)d_in[14];
    const float* bc     = (const float*)d_in[15];
    float* out = (float*)d_out;
    float* ws  = (float*)d_ws;

    float* hA  = ws;                // 819200
    float* hB  = ws + 819200;       // 819200
    float* hw  = ws + 1638400;      // hw during encoder; Z after
    float* A   = ws + 2457600;      // A during encoder
    float* P0  = ws + 2457600;      // P0 overlays A after encoder
    float* WqT = ws + 4915200;      // 16384

    // fused: embed + adj + Wq transpose + predict + zero (all independent parts)
    hipLaunchKernelGGL(k_pre0, dim3(6739), dim3(256), 0, stream,
                       node, demand, Wn0, bn0, dis, We, be, Wc, bc, Wq,
                       hA, A, WqT, out + O3, out + O4);

    float* cur = hA;
    float* nxt = hB;
    for (int l = 0; l < 3; l++) {
        hipLaunchKernelGGL(k_hw16, dim3(400), dim3(256), 0, stream, cur, Wngh + l * 16384, hw);
        hipLaunchKernelGGL(k_agg10, dim3(640), dim3(256), 0, stream, cur, Ws + l * 16384, A, hw, nxt);
        float* tswap = cur; cur = nxt; nxt = tswap;
    }
    // cur == hB holds the final encoder output

    hipLaunchKernelGGL(k_zp, dim3(400, 4), dim3(256), 0, stream, cur, WqT, Wih, bih, hw, P0);

    hipLaunchKernelGGL(k_decode11, dim3(64), dim3(768), 0, stream,
                       P0, hw, dis, Wih, Whh, bih, bhh, out);
}